// Round 7
// baseline (466.901 us; speedup 1.0000x reference)
//
#include <hip/hip_runtime.h>

// ---------------------------------------------------------------------------
// InterModalityUpdate: B=8, NO=512, O=1024, H=16, DH=64. M = 4096 rows.
// Strategy: split-bf16 (3xMFMA) emulated-fp32 GEMMs + single-bf16 MFMA attn.
// R4: XCD swizzle everywhere; proj = 2-MFMA split.
// R5: sgemm_core -> double-buffered counted-vmcnt pipeline (T4): issue next
//     tile's global_load_lds BEFORE waiting, wait vmcnt(8) (prev tile only),
//     raw s_barrier (no compiler vmcnt(0) drain).
// ---------------------------------------------------------------------------

typedef float  f32x4  __attribute__((ext_vector_type(4)));
typedef short  bf16x8 __attribute__((ext_vector_type(8)));
typedef unsigned short u16;
typedef unsigned short u16x8v __attribute__((ext_vector_type(8)));

constexpr float ATT_SCALE = 0.125f;     // 1/sqrt(64)
constexpr float NEGS      = -1.25e8f;   // (-1e9) * SCALE (mask applied before scale)

#define MiB (size_t(1) << 20)
// ---- workspace layout (bytes). Peak live = 108 MiB.
constexpr size_t O_VR_H = 0*MiB,  O_VR_L = 8*MiB;    // relu-split v (F-tiled)
constexpr size_t O_QR_H = 16*MiB, O_QR_L = 24*MiB;   // relu-split q
constexpr size_t O_KR_H = 32*MiB, O_KR_L = 40*MiB;   // relu-split k
constexpr size_t O_WP   = 48*MiB;                    // 5 proj W chunks: hi@48+4z, lo@50+4z
constexpr size_t O_PO   = 68*MiB;                    // proj outs bf16 row-major: z*8MiB
                                                     // {v_q,q_k,q_v,k_k,k_q}
constexpr size_t O_VT0  = 0*MiB,  O_VT1 = 8*MiB;     // q_v^T, k_q^T  [b][h][64d][512key]
constexpr size_t O_OVQ_H= 16*MiB, O_OVQ_L= 24*MiB;   // attn out vq split (F-tiled)
constexpr size_t O_OVK_H= 32*MiB, O_OVK_L= 40*MiB;   // attn out vk split
constexpr size_t O_V2_H = 48*MiB, O_V2_L = 56*MiB;   // v (no relu) split
constexpr size_t O_WVO_H= 64*MiB, O_WVO_L= 68*MiB;   // Wvo^T split (K=2048)
constexpr size_t O_WKO_H= 72*MiB, O_WKO_L= 78*MiB;   // Wko^T split (K=3072)

// ---- helpers ---------------------------------------------------------------
__device__ __forceinline__ u16 f2bf_rne(float x) {
  unsigned u = __float_as_uint(x);
  return (u16)((u + 0x7FFFu + ((u >> 16) & 1u)) >> 16);
}
__device__ __forceinline__ float bf2f(u16 h) {
  return __uint_as_float(((unsigned)h) << 16);
}
__device__ __forceinline__ void gload16(const void* g, void* l) {
  __builtin_amdgcn_global_load_lds(
      (const __attribute__((address_space(1))) unsigned int*)g,
      (__attribute__((address_space(3))) unsigned int*)l, 16, 0, 0);
}
// bijective XCD swizzle: nwg % 8 == 0 required (holds for all our grids)
template <int NWG>
__device__ __forceinline__ int xcd_swz(int bid) {
  return (bid & 7) * (NWG >> 3) + (bid >> 3);
}

// ---------------------------------------------------------------------------
// prep_act: fp32 [4096][1024] -> split bf16 hi/lo in F-tiled layout
//   F layout: chunk idx = ((rt*32 + kt)*4 + kg)*128 + r  holds 8 consecutive k.
// ---------------------------------------------------------------------------
__global__ __launch_bounds__(256) void prep_act(
    const float* __restrict__ s0, const float* __restrict__ s1, const float* __restrict__ s2,
    char* __restrict__ ws, const int relu,
    const size_t o0h, const size_t o0l, const size_t o1h, const size_t o1l,
    const size_t o2h, const size_t o2l)
{
  const int z = blockIdx.z;
  const float* src = (z == 0) ? s0 : (z == 1) ? s1 : s2;
  u16* dh = (u16*)(ws + ((z == 0) ? o0h : (z == 1) ? o1h : o2h));
  u16* dl = (u16*)(ws + ((z == 0) ? o0l : (z == 1) ? o1l : o2l));
  const int idx = blockIdx.x * 256 + threadIdx.x;          // 0..524287
  const int r = idx & 127, kg = (idx >> 7) & 3, kt = (idx >> 9) & 31, rt = idx >> 14;
  const float* p = src + (size_t)(rt * 128 + r) * 1024 + kt * 32 + kg * 8;
  const float4 x0 = ((const float4*)p)[0];
  const float4 x1 = ((const float4*)p)[1];
  const float xv[8] = {x0.x, x0.y, x0.z, x0.w, x1.x, x1.y, x1.z, x1.w};
  u16x8v hv, lv;
#pragma unroll
  for (int e = 0; e < 8; ++e) {
    const float x = relu ? fmaxf(xv[e], 0.f) : xv[e];
    const u16 hi = f2bf_rne(x);
    hv[e] = hi;
    lv[e] = f2bf_rne(x - bf2f(hi));
  }
  *(u16x8v*)(dh + (size_t)idx * 8) = hv;
  *(u16x8v*)(dl + (size_t)idx * 8) = lv;
}

// ---------------------------------------------------------------------------
// prep_w: W [K][N-chunk] fp32 (row stride ld, col offset c0) -> W^T split F-tiled
// mode 0: 5 proj chunks (z);  mode 1: Wvo (K=2048);  mode 2: Wko (K=3072)
// ---------------------------------------------------------------------------
__global__ __launch_bounds__(256) void prep_w(
    const float* __restrict__ W0, const float* __restrict__ W1, const float* __restrict__ W2,
    char* __restrict__ ws, const int mode)
{
  __shared__ float T[32][129];
  const int kt = blockIdx.x, ntile = blockIdx.y, z = blockIdx.z;
  const float* src; int ld, c0, nkt; u16 *dh, *dl;
  if (mode == 0) {
    const int c0s[5] = {1024, 0, 2048, 0, 1024};
    src = (z == 0) ? W0 : (z <= 2) ? W1 : W2;
    ld = 3072; c0 = c0s[z]; nkt = 32;
    dh = (u16*)(ws + O_WP + (size_t)z * 4 * MiB);
    dl = (u16*)(ws + O_WP + (size_t)z * 4 * MiB + 2 * MiB);
  } else if (mode == 1) {
    src = W0; ld = 1024; c0 = 0; nkt = 64;
    dh = (u16*)(ws + O_WVO_H); dl = (u16*)(ws + O_WVO_L);
  } else {
    src = W0; ld = 1024; c0 = 0; nkt = 96;
    dh = (u16*)(ws + O_WKO_H); dl = (u16*)(ws + O_WKO_L);
  }
  const int tid = threadIdx.x;
#pragma unroll
  for (int j = 0; j < 4; ++j) {
    const int p = tid + j * 256;
    const int row = p >> 5, c4 = p & 31;
    const float4 v = *(const float4*)(src + (size_t)(kt * 32 + row) * ld + c0 + ntile * 128 + c4 * 4);
    T[row][c4 * 4 + 0] = v.x; T[row][c4 * 4 + 1] = v.y;
    T[row][c4 * 4 + 2] = v.z; T[row][c4 * 4 + 3] = v.w;
  }
  __syncthreads();
#pragma unroll
  for (int j = 0; j < 2; ++j) {
    const int c = tid + j * 256;
    const int kg = c >> 7, rr = c & 127;
    u16x8v hv, lv;
#pragma unroll
    for (int e = 0; e < 8; ++e) {
      const float x = T[kg * 8 + e][rr];
      const u16 hi = f2bf_rne(x);
      hv[e] = hi;
      lv[e] = f2bf_rne(x - bf2f(hi));
    }
    const size_t off = (size_t)(ntile * nkt + kt) * 4096 + (size_t)c * 8;
    *(u16x8v*)(dh + off) = hv;
    *(u16x8v*)(dl + off) = lv;
  }
}

// ---------------------------------------------------------------------------
// sgemm_core<NM>: C128x128 = sum over parts of A_part @ B, split-bf16.
// NM=3: hh + hl + lh (full split, for out_gemm). 4 staging buffers.
// NM=2: hh + lh only (proj; output bf16-rounded anyway). 3 staging buffers.
// R5 pipeline: double-buffered LDS; per kt each staging wave issues the NEXT
// tile's 8 global_load_lds, then waits vmcnt(8) (prev tile landed, next 8
// stay in flight across the raw barrier). No vmcnt(0) drain in steady state.
// ---------------------------------------------------------------------------
template <int NM>
__device__ __forceinline__ void sgemm_core(
    const u16* __restrict__ a0h, const u16* __restrict__ a0l,
    const u16* __restrict__ a1h, const u16* __restrict__ a1l,
    const u16* __restrict__ a2h, const u16* __restrict__ a2l,
    const u16* __restrict__ bh,  const u16* __restrict__ bl,
    const int nkt, const int mt, const int nt, f32x4 acc[4][4])
{
  constexpr int NB = (NM == 3) ? 4 : 3;
  __shared__ __align__(16) u16 lds[2][NB][4096];
  const int tid = threadIdx.x;
  const int wid = tid >> 6, lane = tid & 63;
  const int lr = lane & 15, lg = lane >> 4;
  const int wm = (wid >> 1) * 64, wn = (wid & 1) * 64;

  auto issue = [&](int kt, int buf) {
    const int p = kt >> 5, kk = kt & 31;
    const u16* ah = (p == 0) ? a0h : (p == 1) ? a1h : a2h;
    const u16* al = (p == 0) ? a0l : (p == 1) ? a1l : a2l;
    const u16* src = nullptr;
    if      (wid == 0) src = ah + (size_t)(mt * 32 + kk) * 4096;
    else if (wid == 1) src = al + (size_t)(mt * 32 + kk) * 4096;
    else if (wid == 2) src = bh + (size_t)(nt * nkt + kt) * 4096;
    else if (NM == 3)  src = bl + (size_t)(nt * nkt + kt) * 4096;
    if (wid < NB) {
      const u16* s = src + lane * 8;
      u16* d = &lds[buf][wid][lane * 8];
#pragma unroll
      for (int i = 0; i < 8; ++i)
        gload16(s + i * 512, d + i * 512);
    }
  };

  issue(0, 0);
  for (int kt = 0; kt < nkt; ++kt) {
    const int cur = kt & 1;
    if (kt + 1 < nkt) {
      issue(kt + 1, cur ^ 1);
      asm volatile("s_waitcnt vmcnt(8)" ::: "memory");
    } else {
      asm volatile("s_waitcnt vmcnt(0)" ::: "memory");
    }
    __builtin_amdgcn_s_barrier();
    __builtin_amdgcn_sched_barrier(0);

    bf16x8 afh[4], afl[4], bfh[4], bfl[4];
#pragma unroll
    for (int i = 0; i < 4; ++i) {
      const int ra = wm + i * 16 + lr;
      const int rb = wn + i * 16 + lr;
      afh[i] = *(const bf16x8*)&lds[cur][0][(lg * 128 + ra) * 8];
      afl[i] = *(const bf16x8*)&lds[cur][1][(lg * 128 + ra) * 8];
      bfh[i] = *(const bf16x8*)&lds[cur][2][(lg * 128 + rb) * 8];
      if (NM == 3) bfl[i] = *(const bf16x8*)&lds[cur][3][(lg * 128 + rb) * 8];
    }
#pragma unroll
    for (int i = 0; i < 4; ++i)
#pragma unroll
      for (int j = 0; j < 4; ++j) {
        acc[i][j] = __builtin_amdgcn_mfma_f32_16x16x32_bf16(afh[i], bfh[j], acc[i][j], 0, 0, 0);
        if (NM == 3)
          acc[i][j] = __builtin_amdgcn_mfma_f32_16x16x32_bf16(afh[i], bfl[j], acc[i][j], 0, 0, 0);
        acc[i][j] = __builtin_amdgcn_mfma_f32_16x16x32_bf16(afl[i], bfh[j], acc[i][j], 0, 0, 0);
      }
    asm volatile("s_waitcnt lgkmcnt(0)" ::: "memory");
    __builtin_amdgcn_s_barrier();
  }
}

// ---------------------------------------------------------------------------
// proj_gemm: 5 chunks; out = bf16((acc + bias) * rowmask), row-major [4096][1024]
// 1-D grid 1280, XCD-swizzled, nt-fastest (A-panel sharers on one XCD).
// ---------------------------------------------------------------------------
__global__ __launch_bounds__(256) void proj_gemm(
    char* __restrict__ ws,
    const float* __restrict__ bv, const float* __restrict__ bq, const float* __restrict__ bk,
    const int* __restrict__ vm, const int* __restrict__ qm, const int* __restrict__ km)
{
  const int swz = xcd_swz<1280>(blockIdx.x);
  const int nt = swz & 7, t = swz >> 3;
  const int mt = t & 31, z = t >> 5;

  const u16* ah = (const u16*)(ws + ((z == 0) ? O_VR_H : (z <= 2) ? O_QR_H : O_KR_H));
  const u16* al = (const u16*)(ws + ((z == 0) ? O_VR_L : (z <= 2) ? O_QR_L : O_KR_L));
  const u16* bh = (const u16*)(ws + O_WP + (size_t)z * 4 * MiB);
  const float* bias = (z == 0) ? bv + 1024 : (z == 1) ? bq : (z == 2) ? bq + 2048
                    : (z == 3) ? bk : bk + 1024;
  const int* msk = (z == 0) ? vm : (z <= 2) ? qm : km;
  u16* out = (u16*)(ws + O_PO + (size_t)z * 8 * MiB);

  f32x4 acc[4][4];
#pragma unroll
  for (int i = 0; i < 4; ++i)
#pragma unroll
    for (int j = 0; j < 4; ++j) {
      f32x4 zer = {0.f, 0.f, 0.f, 0.f};
      acc[i][j] = zer;
    }
  sgemm_core<2>(ah, al, ah, al, ah, al, bh, nullptr, 32, mt, nt, acc);

  const int tid = threadIdx.x, wid = tid >> 6, lane = tid & 63;
  const int lr = lane & 15, lg = lane >> 4;
  const int row0 = mt * 128 + (wid >> 1) * 64;
  const int col0 = nt * 128 + (wid & 1) * 64;
#pragma unroll
  for (int i = 0; i < 4; ++i)
#pragma unroll
    for (int r = 0; r < 4; ++r) {
      const int row = row0 + i * 16 + lg * 4 + r;
      const float mf = (float)msk[row];
#pragma unroll
      for (int j = 0; j < 4; ++j) {
        const int col = col0 + j * 16 + lr;
        out[(size_t)row * 1024 + col] = f2bf_rne((acc[i][j][r] + bias[col]) * mf);
      }
    }
}

// ---------------------------------------------------------------------------
// transpose_vt: bf16 row-major [4096][1024] -> per-(b,h) transposed [64d][512key]
// z=0: q_v -> VT0 ; z=1: k_q -> VT1
// ---------------------------------------------------------------------------
__global__ __launch_bounds__(256) void transpose_vt(char* __restrict__ ws) {
  const int z = blockIdx.z, bh = blockIdx.y, kb = blockIdx.x;
  const u16* src = (const u16*)(ws + O_PO + (size_t)((z == 0) ? 2 : 4) * 8 * MiB);
  u16* dst = (u16*)(ws + ((z == 0) ? O_VT0 : O_VT1));
  __shared__ __align__(16) u16 T[64][80];
  const int tid = threadIdx.x;
  const int b = bh >> 4, h = bh & 15;
#pragma unroll
  for (int j = 0; j < 2; ++j) {
    const int p = tid + j * 256;
    const int row = p >> 3, sl = p & 7;   // row = key-in-tile, sl = 8-u16 slot of d
    const u16x8v val = *(const u16x8v*)(src + (size_t)(b * 512 + kb * 64 + row) * 1024 + h * 64 + sl * 8);
    *(u16x8v*)&T[row][sl * 8] = val;
  }
  __syncthreads();
#pragma unroll
  for (int j = 0; j < 2; ++j) {
    const int p = tid + j * 256;
    const int d = p >> 3, ks = p & 7;
    u16x8v val;
#pragma unroll
    for (int e = 0; e < 8; ++e) val[e] = T[ks * 8 + e][d];
    *(u16x8v*)(dst + (size_t)(bh * 64 + d) * 512 + kb * 64 + ks * 8) = val;
  }
}

// ---------------------------------------------------------------------------
// attn_kernel: flash attention, bf16 MFMA. 1-D grid 2048, XCD-swizzled so the
// 8 q-tiles sharing one (b,att,h)'s K/V are XCD-contiguous.
// 4 waves; wave w owns q-rows [w*16, w*16+16). Tiles 64x64 bf16 in LDS with
// XOR swizzle (slot ^= row&7) via pre-swizzled global_load_lds source.
// Output written directly as split-bf16 F-tiled (out-GEMM A operand).
// ---------------------------------------------------------------------------
__global__ __launch_bounds__(256) void attn_kernel(
    char* __restrict__ ws, const int* __restrict__ qm, const int* __restrict__ km)
{
  __shared__ __align__(16) u16 Qs[4096], Ks[4096], Vs[4096];
  __shared__ __align__(16) float Ps[4][16 * 68];
  __shared__ int msk[64];
  const int swz = xcd_swz<2048>(blockIdx.x);
  const int qt = swz & 7, h = (swz >> 3) & 15, zz = swz >> 7;
  const int b = zz >> 1, att = zz & 1;
  const int q0 = qt * 64;
  const u16 *Qg, *Kg, *VTg; const int* mg; u16 *Ohp, *Olp;
  if (att == 0) {
    Qg  = (const u16*)(ws + O_PO + 0 * 8 * MiB);   // v_q
    Kg  = (const u16*)(ws + O_PO + 1 * 8 * MiB);   // q_k
    VTg = (const u16*)(ws + O_VT0);                // q_v^T
    mg = qm; Ohp = (u16*)(ws + O_OVQ_H); Olp = (u16*)(ws + O_OVQ_L);
  } else {
    Qg  = (const u16*)(ws + O_PO + 4 * 8 * MiB);   // k_q
    Kg  = (const u16*)(ws + O_PO + 3 * 8 * MiB);   // k_k
    VTg = (const u16*)(ws + O_VT1);                // k_q^T
    mg = km; Ohp = (u16*)(ws + O_OVK_H); Olp = (u16*)(ws + O_OVK_L);
  }
  const int tid = threadIdx.x, wid = tid >> 6, lane = tid & 63;
  const int lr = lane & 15, lg = lane >> 4;

  // stage Q once (swizzled)
#pragma unroll
  for (int i = 0; i < 2; ++i) {
    const int p = wid * 128 + i * 64 + lane;
    const int row = p >> 3, sl = p & 7;
    const u16* src = Qg + (size_t)(b * 512 + q0 + row) * 1024 + h * 64 + ((sl ^ (row & 7)) * 8);
    gload16(src, &Qs[(wid * 128 + i * 64) * 8]);
  }
  __syncthreads();
  const int qrow = wid * 16 + lr;
  const bf16x8 qa0 = *(const bf16x8*)&Qs[(qrow * 8 + ((0 + lg) ^ (qrow & 7))) * 8];
  const bf16x8 qa1 = *(const bf16x8*)&Qs[(qrow * 8 + ((4 + lg) ^ (qrow & 7))) * 8];

  f32x4 oacc[4];
  float mreg[4], lreg[4];
#pragma unroll
  for (int i = 0; i < 4; ++i) {
    f32x4 zer = {0.f, 0.f, 0.f, 0.f};
    oacc[i] = zer; mreg[i] = -3.0e38f; lreg[i] = 0.f;
  }

  for (int kt = 0; kt < 8; ++kt) {
    __syncthreads();
#pragma unroll
    for (int i = 0; i < 2; ++i) {
      const int p = wid * 128 + i * 64 + lane;
      const int row = p >> 3, sl = p & 7;
      const u16* ksrc = Kg + (size_t)(b * 512 + kt * 64 + row) * 1024 + h * 64 + ((sl ^ (row & 7)) * 8);
      gload16(ksrc, &Ks[(wid * 128 + i * 64) * 8]);
      const u16* vsrc = VTg + (size_t)((b * 16 + h) * 64 + row) * 512 + kt * 64 + ((sl ^ (row & 7)) * 8);
      gload16(vsrc, &Vs[(wid * 128 + i * 64) * 8]);
    }
    if (tid < 64) msk[tid] = mg[b * 512 + kt * 64 + tid];
    __syncthreads();

    // S = Q K^T   (C: row q = lg*4+r, col key = nt*16+lr)
    f32x4 s[4];
#pragma unroll
    for (int nt = 0; nt < 4; ++nt) {
      f32x4 zer = {0.f, 0.f, 0.f, 0.f};
      s[nt] = zer;
      const int kr = nt * 16 + lr;
      const bf16x8 kb0 = *(const bf16x8*)&Ks[(kr * 8 + ((0 + lg) ^ (kr & 7))) * 8];
      const bf16x8 kb1 = *(const bf16x8*)&Ks[(kr * 8 + ((4 + lg) ^ (kr & 7))) * 8];
      s[nt] = __builtin_amdgcn_mfma_f32_16x16x32_bf16(qa0, kb0, s[nt], 0, 0, 0);
      s[nt] = __builtin_amdgcn_mfma_f32_16x16x32_bf16(qa1, kb1, s[nt], 0, 0, 0);
    }
    // mask (before scale, per reference) then scale
#pragma unroll
    for (int nt = 0; nt < 4; ++nt) {
      const int mk = msk[nt * 16 + lr];
#pragma unroll
      for (int r = 0; r < 4; ++r)
        s[nt][r] = mk ? s[nt][r] * ATT_SCALE : NEGS;
    }
    // online softmax per q-row
#pragma unroll
    for (int r = 0; r < 4; ++r) {
      float mx = fmaxf(fmaxf(s[0][r], s[1][r]), fmaxf(s[2][r], s[3][r]));
      mx = fmaxf(mx, __shfl_xor(mx, 1)); mx = fmaxf(mx, __shfl_xor(mx, 2));
      mx = fmaxf(mx, __shfl_xor(mx, 4)); mx = fmaxf(mx, __shfl_xor(mx, 8));
      const float nm = fmaxf(mreg[r], mx);
      const float corr = __expf(mreg[r] - nm);
      float ps = 0.f;
#pragma unroll
      for (int nt = 0; nt < 4; ++nt) {
        const float pv = __expf(s[nt][r] - nm);
        s[nt][r] = pv; ps += pv;
      }
      ps += __shfl_xor(ps, 1); ps += __shfl_xor(ps, 2);
      ps += __shfl_xor(ps, 4); ps += __shfl_xor(ps, 8);
      lreg[r] = lreg[r] * corr + ps;
      mreg[r] = nm;
#pragma unroll
      for (int d = 0; d < 4; ++d) oacc[d][r] *= corr;
    }
    // P -> wave-private LDS [16 q][68 key] (f32), then PV
    float* Pw = &Ps[wid][0];
#pragma unroll
    for (int nt = 0; nt < 4; ++nt)
#pragma unroll
      for (int r = 0; r < 4; ++r)
        Pw[(lg * 4 + r) * 68 + nt * 16 + lr] = s[nt][r];
#pragma unroll
    for (int ks = 0; ks < 2; ++ks) {
      const float* pp = &Pw[lr * 68 + ks * 32 + lg * 8];
      const f32x4 p0 = *(const f32x4*)pp;
      const f32x4 p1 = *(const f32x4*)(pp + 4);
      bf16x8 pa;
      pa[0] = (short)f2bf_rne(p0[0]); pa[1] = (short)f2bf_rne(p0[1]);
      pa[2] = (short)f2bf_rne(p0[2]); pa[3] = (short)f2bf_rne(p0[3]);
      pa[4] = (short)f2bf_rne(p1[0]); pa[5] = (short)f2bf_rne(p1[1]);
      pa[6] = (short)f2bf_rne(p1[2]); pa[7] = (short)f2bf_rne(p1[3]);
#pragma unroll
      for (int d = 0; d < 4; ++d) {
        const int vr = d * 16 + lr;
        const bf16x8 vb = *(const bf16x8*)&Vs[(vr * 8 + ((ks * 4 + lg) ^ (vr & 7))) * 8];
        oacc[d] = __builtin_amdgcn_mfma_f32_16x16x32_bf16(pa, vb, oacc[d], 0, 0, 0);
      }
    }
  }

  // epilogue: O/l, split to hi/lo, store in F-tiled layout (out-GEMM operand)
#pragma unroll
  for (int r = 0; r < 4; ++r) {
    const float inv = 1.0f / lreg[r];
    const int row = b * 512 + q0 + wid * 16 + lg * 4 + r;
    const int rt = row >> 7, rr = row & 127;
#pragma unroll
    for (int d = 0; d < 4; ++d) {
      const int col = h * 64 + d * 16 + lr;
      const int ktc = col >> 5, kg = (col >> 3) & 3, e = col & 7;
      const size_t off = ((((size_t)rt * 32 + ktc) * 4 + kg) * 128 + rr) * 8 + e;
      const float x = oacc[d][r] * inv;
      const u16 hi = f2bf_rne(x);
      Ohp[off] = hi;
      Olp[off] = f2bf_rne(x - bf2f(hi));
    }
  }
}

// ---------------------------------------------------------------------------
// out_gemm: z=0: [v|vq]@Wvo+bvo -> d_out+4M ; z=1: [v|vq|vk]@Wko+bko -> d_out
// 1-D grid 512, XCD-swizzled; decomposition (nt,z,mt) balances z across XCDs
// and gives 16 in-XCD blocks per A-panel.
// ---------------------------------------------------------------------------
__global__ __launch_bounds__(256) void out_gemm(
    char* __restrict__ ws, const float* __restrict__ bvo, const float* __restrict__ bko,
    float* __restrict__ dout)
{
  const int swz = xcd_swz<512>(blockIdx.x);
  const int nt = swz & 7, z = (swz >> 3) & 1, mt = swz >> 4;

  const u16* a0h = (const u16*)(ws + O_V2_H);
  const u16* a0l = (const u16*)(ws + O_V2_L);
  const u16* a1h = (const u16*)(ws + O_OVQ_H);
  const u16* a1l = (const u16*)(ws + O_OVQ_L);
  const u16* a2h = (const u16*)(ws + O_OVK_H);
  const u16* a2l = (const u16*)(ws + O_OVK_L);
  const int nkt = z ? 96 : 64;
  const u16* bh = (const u16*)(ws + (z ? O_WKO_H : O_WVO_H));
  const u16* bl = (const u16*)(ws + (z ? O_WKO_L : O_WVO_L));
  const float* bias = z ? bko : bvo;
  float* dst = z ? dout : (dout + (size_t)4096 * 1024);

  f32x4 acc[4][4];
#pragma unroll
  for (int i = 0; i < 4; ++i)
#pragma unroll
    for (int j = 0; j < 4; ++j) {
      f32x4 zer = {0.f, 0.f, 0.f, 0.f};
      acc[i][j] = zer;
    }
  sgemm_core<3>(a0h, a0l, a1h, a1l, a2h, a2l, bh, bl, nkt, mt, nt, acc);

  const int tid = threadIdx.x, wid = tid >> 6, lane = tid & 63;
  const int lr = lane & 15, lg = lane >> 4;
  const int row0 = mt * 128 + (wid >> 1) * 64;
  const int col0 = nt * 128 + (wid & 1) * 64;
#pragma unroll
  for (int i = 0; i < 4; ++i)
#pragma unroll
    for (int r = 0; r < 4; ++r) {
      const int row = row0 + i * 16 + lg * 4 + r;
#pragma unroll
      for (int j = 0; j < 4; ++j) {
        const int col = col0 + j * 16 + lr;
        dst[(size_t)row * 1024 + col] = acc[i][j][r] + bias[col];
      }
    }
}

// ---------------------------------------------------------------------------
extern "C" void kernel_launch(void* const* d_in, const int* in_sizes, int n_in,
                              void* d_out, int out_size, void* d_ws, size_t ws_size,
                              hipStream_t stream) {
  const float* v  = (const float*)d_in[0];
  const float* q  = (const float*)d_in[1];
  const float* k  = (const float*)d_in[2];
  const int* vm   = (const int*)d_in[3];
  const int* qm   = (const int*)d_in[4];
  const int* km   = (const int*)d_in[5];
  const float* Wv = (const float*)d_in[6];
  const float* bv = (const float*)d_in[7];
  const float* Wq = (const float*)d_in[8];
  const float* bq = (const float*)d_in[9];
  const float* Wk = (const float*)d_in[10];
  const float* bk = (const float*)d_in[11];
  const float* Wvo = (const float*)d_in[12];
  const float* bvo = (const float*)d_in[13];
  const float* Wko = (const float*)d_in[14];
  const float* bko = (const float*)d_in[15];
  char* ws = (char*)d_ws;
  float* out = (float*)d_out;

  // Phase A: split/tiling converts for projections
  prep_act<<<dim3(2048, 1, 3), 256, 0, stream>>>(v, q, k, ws, 1,
      O_VR_H, O_VR_L, O_QR_H, O_QR_L, O_KR_H, O_KR_L);
  prep_w<<<dim3(32, 8, 5), 256, 0, stream>>>(Wv, Wq, Wk, ws, 0);
  // Phase B: 5 projection GEMMs (2-MFMA split) -> bf16 row-major
  proj_gemm<<<dim3(1280), 256, 0, stream>>>(ws, bv, bq, bk, vm, qm, km);
  // Phase C: transpose value tensors for PV
  transpose_vt<<<dim3(8, 128, 2), 256, 0, stream>>>(ws);
  // Phase D: both attentions -> split-tiled O
  attn_kernel<<<dim3(2048), 256, 0, stream>>>(ws, qm, km);
  // Phase E: split/tiling converts for output GEMMs
  prep_act<<<dim3(2048, 1, 1), 256, 0, stream>>>(v, v, v, ws, 0,
      O_V2_H, O_V2_L, O_V2_H, O_V2_L, O_V2_H, O_V2_L);
  prep_w<<<dim3(64, 8, 1), 256, 0, stream>>>(Wvo, Wvo, Wvo, ws, 1);
  prep_w<<<dim3(96, 8, 1), 256, 0, stream>>>(Wko, Wko, Wko, ws, 2);
  // Phase F: output GEMMs -> d_out = [updated_V ; updated_v]
  out_gemm<<<dim3(512), 256, 0, stream>>>(ws, bvo, bko, out);
}

// Round 8
// 445.634 us; speedup vs baseline: 1.0477x; 1.0477x over previous
//
#include <hip/hip_runtime.h>

// ---------------------------------------------------------------------------
// InterModalityUpdate: B=8, NO=512, O=1024, H=16, DH=64. M = 4096 rows.
// Strategy: split-bf16 (3xMFMA) emulated-fp32 GEMMs + single-bf16 MFMA attn.
// R4: XCD swizzle everywhere; proj = 2-MFMA split.  (462 us measured)
// R5 counted-vmcnt pipeline REGRESSED (147us out_gemm) -> reverted.
// R7: BK=64 (halve barrier-drain events per GEMM); numerics identical to R4.
// ---------------------------------------------------------------------------

typedef float  f32x4  __attribute__((ext_vector_type(4)));
typedef short  bf16x8 __attribute__((ext_vector_type(8)));
typedef unsigned short u16;
typedef unsigned short u16x8v __attribute__((ext_vector_type(8)));

constexpr float ATT_SCALE = 0.125f;     // 1/sqrt(64)
constexpr float NEGS      = -1.25e8f;   // (-1e9) * SCALE (mask applied before scale)

#define MiB (size_t(1) << 20)
// ---- workspace layout (bytes). Peak live = 108 MiB.
constexpr size_t O_VR_H = 0*MiB,  O_VR_L = 8*MiB;    // relu-split v (F-tiled)
constexpr size_t O_QR_H = 16*MiB, O_QR_L = 24*MiB;   // relu-split q
constexpr size_t O_KR_H = 32*MiB, O_KR_L = 40*MiB;   // relu-split k
constexpr size_t O_WP   = 48*MiB;                    // 5 proj W chunks: hi@48+4z, lo@50+4z
constexpr size_t O_PO   = 68*MiB;                    // proj outs bf16 row-major: z*8MiB
                                                     // {v_q,q_k,q_v,k_k,k_q}
constexpr size_t O_VT0  = 0*MiB,  O_VT1 = 8*MiB;     // q_v^T, k_q^T  [b][h][64d][512key]
constexpr size_t O_OVQ_H= 16*MiB, O_OVQ_L= 24*MiB;   // attn out vq split (F-tiled)
constexpr size_t O_OVK_H= 32*MiB, O_OVK_L= 40*MiB;   // attn out vk split
constexpr size_t O_V2_H = 48*MiB, O_V2_L = 56*MiB;   // v (no relu) split
constexpr size_t O_WVO_H= 64*MiB, O_WVO_L= 68*MiB;   // Wvo^T split (K=2048)
constexpr size_t O_WKO_H= 72*MiB, O_WKO_L= 78*MiB;   // Wko^T split (K=3072)

// ---- helpers ---------------------------------------------------------------
__device__ __forceinline__ u16 f2bf_rne(float x) {
  unsigned u = __float_as_uint(x);
  return (u16)((u + 0x7FFFu + ((u >> 16) & 1u)) >> 16);
}
__device__ __forceinline__ float bf2f(u16 h) {
  return __uint_as_float(((unsigned)h) << 16);
}
__device__ __forceinline__ void gload16(const void* g, void* l) {
  __builtin_amdgcn_global_load_lds(
      (const __attribute__((address_space(1))) unsigned int*)g,
      (__attribute__((address_space(3))) unsigned int*)l, 16, 0, 0);
}
// bijective XCD swizzle: nwg % 8 == 0 required (holds for all our grids)
template <int NWG>
__device__ __forceinline__ int xcd_swz(int bid) {
  return (bid & 7) * (NWG >> 3) + (bid >> 3);
}

// ---------------------------------------------------------------------------
// prep_act: fp32 [4096][1024] -> split bf16 hi/lo in F-tiled layout
//   F layout: chunk idx = ((rt*32 + kt)*4 + kg)*128 + r  holds 8 consecutive k.
// ---------------------------------------------------------------------------
__global__ __launch_bounds__(256) void prep_act(
    const float* __restrict__ s0, const float* __restrict__ s1, const float* __restrict__ s2,
    char* __restrict__ ws, const int relu,
    const size_t o0h, const size_t o0l, const size_t o1h, const size_t o1l,
    const size_t o2h, const size_t o2l)
{
  const int z = blockIdx.z;
  const float* src = (z == 0) ? s0 : (z == 1) ? s1 : s2;
  u16* dh = (u16*)(ws + ((z == 0) ? o0h : (z == 1) ? o1h : o2h));
  u16* dl = (u16*)(ws + ((z == 0) ? o0l : (z == 1) ? o1l : o2l));
  const int idx = blockIdx.x * 256 + threadIdx.x;          // 0..524287
  const int r = idx & 127, kg = (idx >> 7) & 3, kt = (idx >> 9) & 31, rt = idx >> 14;
  const float* p = src + (size_t)(rt * 128 + r) * 1024 + kt * 32 + kg * 8;
  const float4 x0 = ((const float4*)p)[0];
  const float4 x1 = ((const float4*)p)[1];
  const float xv[8] = {x0.x, x0.y, x0.z, x0.w, x1.x, x1.y, x1.z, x1.w};
  u16x8v hv, lv;
#pragma unroll
  for (int e = 0; e < 8; ++e) {
    const float x = relu ? fmaxf(xv[e], 0.f) : xv[e];
    const u16 hi = f2bf_rne(x);
    hv[e] = hi;
    lv[e] = f2bf_rne(x - bf2f(hi));
  }
  *(u16x8v*)(dh + (size_t)idx * 8) = hv;
  *(u16x8v*)(dl + (size_t)idx * 8) = lv;
}

// ---------------------------------------------------------------------------
// prep_w: W [K][N-chunk] fp32 (row stride ld, col offset c0) -> W^T split F-tiled
// mode 0: 5 proj chunks (z);  mode 1: Wvo (K=2048);  mode 2: Wko (K=3072)
// ---------------------------------------------------------------------------
__global__ __launch_bounds__(256) void prep_w(
    const float* __restrict__ W0, const float* __restrict__ W1, const float* __restrict__ W2,
    char* __restrict__ ws, const int mode)
{
  __shared__ float T[32][129];
  const int kt = blockIdx.x, ntile = blockIdx.y, z = blockIdx.z;
  const float* src; int ld, c0, nkt; u16 *dh, *dl;
  if (mode == 0) {
    const int c0s[5] = {1024, 0, 2048, 0, 1024};
    src = (z == 0) ? W0 : (z <= 2) ? W1 : W2;
    ld = 3072; c0 = c0s[z]; nkt = 32;
    dh = (u16*)(ws + O_WP + (size_t)z * 4 * MiB);
    dl = (u16*)(ws + O_WP + (size_t)z * 4 * MiB + 2 * MiB);
  } else if (mode == 1) {
    src = W0; ld = 1024; c0 = 0; nkt = 64;
    dh = (u16*)(ws + O_WVO_H); dl = (u16*)(ws + O_WVO_L);
  } else {
    src = W0; ld = 1024; c0 = 0; nkt = 96;
    dh = (u16*)(ws + O_WKO_H); dl = (u16*)(ws + O_WKO_L);
  }
  const int tid = threadIdx.x;
#pragma unroll
  for (int j = 0; j < 4; ++j) {
    const int p = tid + j * 256;
    const int row = p >> 5, c4 = p & 31;
    const float4 v = *(const float4*)(src + (size_t)(kt * 32 + row) * ld + c0 + ntile * 128 + c4 * 4);
    T[row][c4 * 4 + 0] = v.x; T[row][c4 * 4 + 1] = v.y;
    T[row][c4 * 4 + 2] = v.z; T[row][c4 * 4 + 3] = v.w;
  }
  __syncthreads();
#pragma unroll
  for (int j = 0; j < 2; ++j) {
    const int c = tid + j * 256;
    const int kg = c >> 7, rr = c & 127;
    u16x8v hv, lv;
#pragma unroll
    for (int e = 0; e < 8; ++e) {
      const float x = T[kg * 8 + e][rr];
      const u16 hi = f2bf_rne(x);
      hv[e] = hi;
      lv[e] = f2bf_rne(x - bf2f(hi));
    }
    const size_t off = (size_t)(ntile * nkt + kt) * 4096 + (size_t)c * 8;
    *(u16x8v*)(dh + off) = hv;
    *(u16x8v*)(dl + off) = lv;
  }
}

// ---------------------------------------------------------------------------
// sgemm_core<NM>: C128x128 = sum over parts of A_part @ B, split-bf16.
// NM=3: hh + hl + lh (full split, out_gemm), 4 staging buffers.
// NM=2: hh + lh only (proj; output bf16-rounded anyway), 3 staging buffers.
// R4-proven sync structure (syncthreads / stage / syncthreads / compute),
// BK=64: each kt stages two contiguous 8KB F-tiles per operand (16KB/wave)
// and runs 2 k-halves of MFMAs -> half the barrier-drain events vs BK=32.
// nkt is in BK=64 units (K/64).
// ---------------------------------------------------------------------------
template <int NM>
__device__ __forceinline__ void sgemm_core(
    const u16* __restrict__ a0h, const u16* __restrict__ a0l,
    const u16* __restrict__ a1h, const u16* __restrict__ a1l,
    const u16* __restrict__ a2h, const u16* __restrict__ a2l,
    const u16* __restrict__ bh,  const u16* __restrict__ bl,
    const int nkt, const int mt, const int nt, f32x4 acc[4][4])
{
  constexpr int NB = (NM == 3) ? 4 : 3;
  __shared__ __align__(16) u16 lds[NB][8192];
  const int tid = threadIdx.x;
  const int wid = tid >> 6, lane = tid & 63;
  const int lr = lane & 15, lg = lane >> 4;
  const int wm = (wid >> 1) * 64, wn = (wid & 1) * 64;

  for (int kt = 0; kt < nkt; ++kt) {      // kt in BK=64 units
    __syncthreads();
    const int kk2 = kt << 1;              // BK=32 tile index (global)
    const int p = kk2 >> 5, kk = kk2 & 31;
    const u16* ah = (p == 0) ? a0h : (p == 1) ? a1h : a2h;
    const u16* al = (p == 0) ? a0l : (p == 1) ? a1l : a2l;
    const u16* src = nullptr;
    if      (wid == 0) src = ah + (size_t)(mt * 32 + kk) * 4096;
    else if (wid == 1) src = al + (size_t)(mt * 32 + kk) * 4096;
    else if (wid == 2) src = bh + (size_t)(nt * (nkt << 1) + kk2) * 4096;
    else if (NM == 3)  src = bl + (size_t)(nt * (nkt << 1) + kk2) * 4096;
    if (wid < NB) {
      const u16* s = src + lane * 8;
      u16* d = &lds[wid][lane * 8];
#pragma unroll
      for (int i = 0; i < 16; ++i)
        gload16(s + i * 512, d + i * 512);
    }
    __syncthreads();

    for (int h = 0; h < 2; ++h) {         // two k-halves of the 64-wide tile
      const int kg0 = (h * 4 + lg) * 128;
      bf16x8 afh[4], afl[4], bfh[4], bfl[4];
#pragma unroll
      for (int i = 0; i < 4; ++i) {
        const int ra = wm + i * 16 + lr;
        const int rb = wn + i * 16 + lr;
        afh[i] = *(const bf16x8*)&lds[0][(kg0 + ra) * 8];
        afl[i] = *(const bf16x8*)&lds[1][(kg0 + ra) * 8];
        bfh[i] = *(const bf16x8*)&lds[2][(kg0 + rb) * 8];
        if (NM == 3) bfl[i] = *(const bf16x8*)&lds[3][(kg0 + rb) * 8];
      }
#pragma unroll
      for (int i = 0; i < 4; ++i)
#pragma unroll
        for (int j = 0; j < 4; ++j) {
          acc[i][j] = __builtin_amdgcn_mfma_f32_16x16x32_bf16(afh[i], bfh[j], acc[i][j], 0, 0, 0);
          if (NM == 3)
            acc[i][j] = __builtin_amdgcn_mfma_f32_16x16x32_bf16(afh[i], bfl[j], acc[i][j], 0, 0, 0);
          acc[i][j] = __builtin_amdgcn_mfma_f32_16x16x32_bf16(afl[i], bfh[j], acc[i][j], 0, 0, 0);
        }
    }
  }
}

// ---------------------------------------------------------------------------
// proj_gemm: 5 chunks; out = bf16((acc + bias) * rowmask), row-major [4096][1024]
// 1-D grid 1280, XCD-swizzled, nt-fastest (A-panel sharers on one XCD).
// ---------------------------------------------------------------------------
__global__ __launch_bounds__(256) void proj_gemm(
    char* __restrict__ ws,
    const float* __restrict__ bv, const float* __restrict__ bq, const float* __restrict__ bk,
    const int* __restrict__ vm, const int* __restrict__ qm, const int* __restrict__ km)
{
  const int swz = xcd_swz<1280>(blockIdx.x);
  const int nt = swz & 7, t = swz >> 3;
  const int mt = t & 31, z = t >> 5;

  const u16* ah = (const u16*)(ws + ((z == 0) ? O_VR_H : (z <= 2) ? O_QR_H : O_KR_H));
  const u16* al = (const u16*)(ws + ((z == 0) ? O_VR_L : (z <= 2) ? O_QR_L : O_KR_L));
  const u16* bh = (const u16*)(ws + O_WP + (size_t)z * 4 * MiB);
  const float* bias = (z == 0) ? bv + 1024 : (z == 1) ? bq : (z == 2) ? bq + 2048
                    : (z == 3) ? bk : bk + 1024;
  const int* msk = (z == 0) ? vm : (z <= 2) ? qm : km;
  u16* out = (u16*)(ws + O_PO + (size_t)z * 8 * MiB);

  f32x4 acc[4][4];
#pragma unroll
  for (int i = 0; i < 4; ++i)
#pragma unroll
    for (int j = 0; j < 4; ++j) {
      f32x4 zer = {0.f, 0.f, 0.f, 0.f};
      acc[i][j] = zer;
    }
  sgemm_core<2>(ah, al, ah, al, ah, al, bh, nullptr, 16, mt, nt, acc);

  const int tid = threadIdx.x, wid = tid >> 6, lane = tid & 63;
  const int lr = lane & 15, lg = lane >> 4;
  const int row0 = mt * 128 + (wid >> 1) * 64;
  const int col0 = nt * 128 + (wid & 1) * 64;
#pragma unroll
  for (int i = 0; i < 4; ++i)
#pragma unroll
    for (int r = 0; r < 4; ++r) {
      const int row = row0 + i * 16 + lg * 4 + r;
      const float mf = (float)msk[row];
#pragma unroll
      for (int j = 0; j < 4; ++j) {
        const int col = col0 + j * 16 + lr;
        out[(size_t)row * 1024 + col] = f2bf_rne((acc[i][j][r] + bias[col]) * mf);
      }
    }
}

// ---------------------------------------------------------------------------
// transpose_vt: bf16 row-major [4096][1024] -> per-(b,h) transposed [64d][512key]
// z=0: q_v -> VT0 ; z=1: k_q -> VT1
// ---------------------------------------------------------------------------
__global__ __launch_bounds__(256) void transpose_vt(char* __restrict__ ws) {
  const int z = blockIdx.z, bh = blockIdx.y, kb = blockIdx.x;
  const u16* src = (const u16*)(ws + O_PO + (size_t)((z == 0) ? 2 : 4) * 8 * MiB);
  u16* dst = (u16*)(ws + ((z == 0) ? O_VT0 : O_VT1));
  __shared__ __align__(16) u16 T[64][80];
  const int tid = threadIdx.x;
  const int b = bh >> 4, h = bh & 15;
#pragma unroll
  for (int j = 0; j < 2; ++j) {
    const int p = tid + j * 256;
    const int row = p >> 3, sl = p & 7;   // row = key-in-tile, sl = 8-u16 slot of d
    const u16x8v val = *(const u16x8v*)(src + (size_t)(b * 512 + kb * 64 + row) * 1024 + h * 64 + sl * 8);
    *(u16x8v*)&T[row][sl * 8] = val;
  }
  __syncthreads();
#pragma unroll
  for (int j = 0; j < 2; ++j) {
    const int p = tid + j * 256;
    const int d = p >> 3, ks = p & 7;
    u16x8v val;
#pragma unroll
    for (int e = 0; e < 8; ++e) val[e] = T[ks * 8 + e][d];
    *(u16x8v*)(dst + (size_t)(bh * 64 + d) * 512 + kb * 64 + ks * 8) = val;
  }
}

// ---------------------------------------------------------------------------
// attn_kernel: flash attention, bf16 MFMA. 1-D grid 2048, XCD-swizzled so the
// 8 q-tiles sharing one (b,att,h)'s K/V are XCD-contiguous.
// 4 waves; wave w owns q-rows [w*16, w*16+16). Tiles 64x64 bf16 in LDS with
// XOR swizzle (slot ^= row&7) via pre-swizzled global_load_lds source.
// Output written directly as split-bf16 F-tiled (out-GEMM A operand).
// ---------------------------------------------------------------------------
__global__ __launch_bounds__(256) void attn_kernel(
    char* __restrict__ ws, const int* __restrict__ qm, const int* __restrict__ km)
{
  __shared__ __align__(16) u16 Qs[4096], Ks[4096], Vs[4096];
  __shared__ __align__(16) float Ps[4][16 * 68];
  __shared__ int msk[64];
  const int swz = xcd_swz<2048>(blockIdx.x);
  const int qt = swz & 7, h = (swz >> 3) & 15, zz = swz >> 7;
  const int b = zz >> 1, att = zz & 1;
  const int q0 = qt * 64;
  const u16 *Qg, *Kg, *VTg; const int* mg; u16 *Ohp, *Olp;
  if (att == 0) {
    Qg  = (const u16*)(ws + O_PO + 0 * 8 * MiB);   // v_q
    Kg  = (const u16*)(ws + O_PO + 1 * 8 * MiB);   // q_k
    VTg = (const u16*)(ws + O_VT0);                // q_v^T
    mg = qm; Ohp = (u16*)(ws + O_OVQ_H); Olp = (u16*)(ws + O_OVQ_L);
  } else {
    Qg  = (const u16*)(ws + O_PO + 4 * 8 * MiB);   // k_q
    Kg  = (const u16*)(ws + O_PO + 3 * 8 * MiB);   // k_k
    VTg = (const u16*)(ws + O_VT1);                // k_q^T
    mg = km; Ohp = (u16*)(ws + O_OVK_H); Olp = (u16*)(ws + O_OVK_L);
  }
  const int tid = threadIdx.x, wid = tid >> 6, lane = tid & 63;
  const int lr = lane & 15, lg = lane >> 4;

  // stage Q once (swizzled)
#pragma unroll
  for (int i = 0; i < 2; ++i) {
    const int p = wid * 128 + i * 64 + lane;
    const int row = p >> 3, sl = p & 7;
    const u16* src = Qg + (size_t)(b * 512 + q0 + row) * 1024 + h * 64 + ((sl ^ (row & 7)) * 8);
    gload16(src, &Qs[(wid * 128 + i * 64) * 8]);
  }
  __syncthreads();
  const int qrow = wid * 16 + lr;
  const bf16x8 qa0 = *(const bf16x8*)&Qs[(qrow * 8 + ((0 + lg) ^ (qrow & 7))) * 8];
  const bf16x8 qa1 = *(const bf16x8*)&Qs[(qrow * 8 + ((4 + lg) ^ (qrow & 7))) * 8];

  f32x4 oacc[4];
  float mreg[4], lreg[4];
#pragma unroll
  for (int i = 0; i < 4; ++i) {
    f32x4 zer = {0.f, 0.f, 0.f, 0.f};
    oacc[i] = zer; mreg[i] = -3.0e38f; lreg[i] = 0.f;
  }

  for (int kt = 0; kt < 8; ++kt) {
    __syncthreads();
#pragma unroll
    for (int i = 0; i < 2; ++i) {
      const int p = wid * 128 + i * 64 + lane;
      const int row = p >> 3, sl = p & 7;
      const u16* ksrc = Kg + (size_t)(b * 512 + kt * 64 + row) * 1024 + h * 64 + ((sl ^ (row & 7)) * 8);
      gload16(ksrc, &Ks[(wid * 128 + i * 64) * 8]);
      const u16* vsrc = VTg + (size_t)((b * 16 + h) * 64 + row) * 512 + kt * 64 + ((sl ^ (row & 7)) * 8);
      gload16(vsrc, &Vs[(wid * 128 + i * 64) * 8]);
    }
    if (tid < 64) msk[tid] = mg[b * 512 + kt * 64 + tid];
    __syncthreads();

    // S = Q K^T   (C: row q = lg*4+r, col key = nt*16+lr)
    f32x4 s[4];
#pragma unroll
    for (int nt = 0; nt < 4; ++nt) {
      f32x4 zer = {0.f, 0.f, 0.f, 0.f};
      s[nt] = zer;
      const int kr = nt * 16 + lr;
      const bf16x8 kb0 = *(const bf16x8*)&Ks[(kr * 8 + ((0 + lg) ^ (kr & 7))) * 8];
      const bf16x8 kb1 = *(const bf16x8*)&Ks[(kr * 8 + ((4 + lg) ^ (kr & 7))) * 8];
      s[nt] = __builtin_amdgcn_mfma_f32_16x16x32_bf16(qa0, kb0, s[nt], 0, 0, 0);
      s[nt] = __builtin_amdgcn_mfma_f32_16x16x32_bf16(qa1, kb1, s[nt], 0, 0, 0);
    }
    // mask (before scale, per reference) then scale
#pragma unroll
    for (int nt = 0; nt < 4; ++nt) {
      const int mk = msk[nt * 16 + lr];
#pragma unroll
      for (int r = 0; r < 4; ++r)
        s[nt][r] = mk ? s[nt][r] * ATT_SCALE : NEGS;
    }
    // online softmax per q-row
#pragma unroll
    for (int r = 0; r < 4; ++r) {
      float mx = fmaxf(fmaxf(s[0][r], s[1][r]), fmaxf(s[2][r], s[3][r]));
      mx = fmaxf(mx, __shfl_xor(mx, 1)); mx = fmaxf(mx, __shfl_xor(mx, 2));
      mx = fmaxf(mx, __shfl_xor(mx, 4)); mx = fmaxf(mx, __shfl_xor(mx, 8));
      const float nm = fmaxf(mreg[r], mx);
      const float corr = __expf(mreg[r] - nm);
      float ps = 0.f;
#pragma unroll
      for (int nt = 0; nt < 4; ++nt) {
        const float pv = __expf(s[nt][r] - nm);
        s[nt][r] = pv; ps += pv;
      }
      ps += __shfl_xor(ps, 1); ps += __shfl_xor(ps, 2);
      ps += __shfl_xor(ps, 4); ps += __shfl_xor(ps, 8);
      lreg[r] = lreg[r] * corr + ps;
      mreg[r] = nm;
#pragma unroll
      for (int d = 0; d < 4; ++d) oacc[d][r] *= corr;
    }
    // P -> wave-private LDS [16 q][68 key] (f32), then PV
    float* Pw = &Ps[wid][0];
#pragma unroll
    for (int nt = 0; nt < 4; ++nt)
#pragma unroll
      for (int r = 0; r < 4; ++r)
        Pw[(lg * 4 + r) * 68 + nt * 16 + lr] = s[nt][r];
#pragma unroll
    for (int ks = 0; ks < 2; ++ks) {
      const float* pp = &Pw[lr * 68 + ks * 32 + lg * 8];
      const f32x4 p0 = *(const f32x4*)pp;
      const f32x4 p1 = *(const f32x4*)(pp + 4);
      bf16x8 pa;
      pa[0] = (short)f2bf_rne(p0[0]); pa[1] = (short)f2bf_rne(p0[1]);
      pa[2] = (short)f2bf_rne(p0[2]); pa[3] = (short)f2bf_rne(p0[3]);
      pa[4] = (short)f2bf_rne(p1[0]); pa[5] = (short)f2bf_rne(p1[1]);
      pa[6] = (short)f2bf_rne(p1[2]); pa[7] = (short)f2bf_rne(p1[3]);
#pragma unroll
      for (int d = 0; d < 4; ++d) {
        const int vr = d * 16 + lr;
        const bf16x8 vb = *(const bf16x8*)&Vs[(vr * 8 + ((ks * 4 + lg) ^ (vr & 7))) * 8];
        oacc[d] = __builtin_amdgcn_mfma_f32_16x16x32_bf16(pa, vb, oacc[d], 0, 0, 0);
      }
    }
  }

  // epilogue: O/l, split to hi/lo, store in F-tiled layout (out-GEMM operand)
#pragma unroll
  for (int r = 0; r < 4; ++r) {
    const float inv = 1.0f / lreg[r];
    const int row = b * 512 + q0 + wid * 16 + lg * 4 + r;
    const int rt = row >> 7, rr = row & 127;
#pragma unroll
    for (int d = 0; d < 4; ++d) {
      const int col = h * 64 + d * 16 + lr;
      const int ktc = col >> 5, kg = (col >> 3) & 3, e = col & 7;
      const size_t off = ((((size_t)rt * 32 + ktc) * 4 + kg) * 128 + rr) * 8 + e;
      const float x = oacc[d][r] * inv;
      const u16 hi = f2bf_rne(x);
      Ohp[off] = hi;
      Olp[off] = f2bf_rne(x - bf2f(hi));
    }
  }
}

// ---------------------------------------------------------------------------
// out_gemm: z=0: [v|vq]@Wvo+bvo -> d_out+4M ; z=1: [v|vq|vk]@Wko+bko -> d_out
// 1-D grid 512, XCD-swizzled; decomposition (nt,z,mt) balances z across XCDs
// and gives 16 in-XCD blocks per A-panel.
// ---------------------------------------------------------------------------
__global__ __launch_bounds__(256) void out_gemm(
    char* __restrict__ ws, const float* __restrict__ bvo, const float* __restrict__ bko,
    float* __restrict__ dout)
{
  const int swz = xcd_swz<512>(blockIdx.x);
  const int nt = swz & 7, z = (swz >> 3) & 1, mt = swz >> 4;

  const u16* a0h = (const u16*)(ws + O_V2_H);
  const u16* a0l = (const u16*)(ws + O_V2_L);
  const u16* a1h = (const u16*)(ws + O_OVQ_H);
  const u16* a1l = (const u16*)(ws + O_OVQ_L);
  const u16* a2h = (const u16*)(ws + O_OVK_H);
  const u16* a2l = (const u16*)(ws + O_OVK_L);
  const int nkt = z ? 48 : 32;                  // BK=64 units
  const u16* bh = (const u16*)(ws + (z ? O_WKO_H : O_WVO_H));
  const u16* bl = (const u16*)(ws + (z ? O_WKO_L : O_WVO_L));
  const float* bias = z ? bko : bvo;
  float* dst = z ? dout : (dout + (size_t)4096 * 1024);

  f32x4 acc[4][4];
#pragma unroll
  for (int i = 0; i < 4; ++i)
#pragma unroll
    for (int j = 0; j < 4; ++j) {
      f32x4 zer = {0.f, 0.f, 0.f, 0.f};
      acc[i][j] = zer;
    }
  sgemm_core<3>(a0h, a0l, a1h, a1l, a2h, a2l, bh, bl, nkt, mt, nt, acc);

  const int tid = threadIdx.x, wid = tid >> 6, lane = tid & 63;
  const int lr = lane & 15, lg = lane >> 4;
  const int row0 = mt * 128 + (wid >> 1) * 64;
  const int col0 = nt * 128 + (wid & 1) * 64;
#pragma unroll
  for (int i = 0; i < 4; ++i)
#pragma unroll
    for (int r = 0; r < 4; ++r) {
      const int row = row0 + i * 16 + lg * 4 + r;
#pragma unroll
      for (int j = 0; j < 4; ++j) {
        const int col = col0 + j * 16 + lr;
        dst[(size_t)row * 1024 + col] = acc[i][j][r] + bias[col];
      }
    }
}

// ---------------------------------------------------------------------------
extern "C" void kernel_launch(void* const* d_in, const int* in_sizes, int n_in,
                              void* d_out, int out_size, void* d_ws, size_t ws_size,
                              hipStream_t stream) {
  const float* v  = (const float*)d_in[0];
  const float* q  = (const float*)d_in[1];
  const float* k  = (const float*)d_in[2];
  const int* vm   = (const int*)d_in[3];
  const int* qm   = (const int*)d_in[4];
  const int* km   = (const int*)d_in[5];
  const float* Wv = (const float*)d_in[6];
  const float* bv = (const float*)d_in[7];
  const float* Wq = (const float*)d_in[8];
  const float* bq = (const float*)d_in[9];
  const float* Wk = (const float*)d_in[10];
  const float* bk = (const float*)d_in[11];
  const float* Wvo = (const float*)d_in[12];
  const float* bvo = (const float*)d_in[13];
  const float* Wko = (const float*)d_in[14];
  const float* bko = (const float*)d_in[15];
  char* ws = (char*)d_ws;
  float* out = (float*)d_out;

  // Phase A: split/tiling converts for projections
  prep_act<<<dim3(2048, 1, 3), 256, 0, stream>>>(v, q, k, ws, 1,
      O_VR_H, O_VR_L, O_QR_H, O_QR_L, O_KR_H, O_KR_L);
  prep_w<<<dim3(32, 8, 5), 256, 0, stream>>>(Wv, Wq, Wk, ws, 0);
  // Phase B: 5 projection GEMMs (2-MFMA split) -> bf16 row-major
  proj_gemm<<<dim3(1280), 256, 0, stream>>>(ws, bv, bq, bk, vm, qm, km);
  // Phase C: transpose value tensors for PV
  transpose_vt<<<dim3(8, 128, 2), 256, 0, stream>>>(ws);
  // Phase D: both attentions -> split-tiled O
  attn_kernel<<<dim3(2048), 256, 0, stream>>>(ws, qm, km);
  // Phase E: split/tiling converts for output GEMMs
  prep_act<<<dim3(2048, 1, 1), 256, 0, stream>>>(v, v, v, ws, 0,
      O_V2_H, O_V2_L, O_V2_H, O_V2_L, O_V2_H, O_V2_L);
  prep_w<<<dim3(64, 8, 1), 256, 0, stream>>>(Wvo, Wvo, Wvo, ws, 1);
  prep_w<<<dim3(96, 8, 1), 256, 0, stream>>>(Wko, Wko, Wko, ws, 2);
  // Phase F: output GEMMs -> d_out = [updated_V ; updated_v]
  out_gemm<<<dim3(512), 256, 0, stream>>>(ws, bvo, bko, out);
}